// Round 5
// baseline (379.883 us; speedup 1.0000x reference)
//
#include <hip/hip_runtime.h>
#include <hip/hip_bf16.h>

constexpr int HID = 256;
constexpr float NEG = 0.2f;
constexpr float EPS = 1e-5f;

typedef __attribute__((ext_vector_type(8))) short bf16x8;
typedef __attribute__((ext_vector_type(4))) float f32x4;

static __device__ __forceinline__ unsigned short f2bf(float f) {
    unsigned u = __builtin_bit_cast(unsigned, f);
    u += 0x7fffu + ((u >> 16) & 1u);
    return (unsigned short)(u >> 16);
}
static __device__ __forceinline__ float bf2f(unsigned short h) {
    return __builtin_bit_cast(float, ((unsigned)h) << 16);
}

// ---------------- fused preprocessing ----------------
// range-partitioned single kernel: init deg/cursor, cvt x->bf16, cls rows,
// fragment W_in and W_gat, batch bounds.
// NOTE: lo/hi are written ONLY by the bounds task (batch covers every graph id,
// so each lo[b]/hi[b] gets exactly one write) — zero-initializing them here
// would race with the bounds blocks (round-4 bug).

__device__ __forceinline__ void frag_task(const float* __restrict__ W,
                                          ushort* __restrict__ out,
                                          int KS, int nmat, int q) {
    int per = KS * 1024;
    if (q >= per * nmat) return;
    int mat = q / per, r = q - mat * per;
    int l = r & 63, nf = (r >> 6) & 15, kk = r >> 10;
    const float* Wm = W + (size_t)mat * KS * 32 * 256;
    int kb = kk * 32 + ((l >> 4) << 3);
    int col = nf * 16 + (l & 15);
    bf16x8 v;
#pragma unroll
    for (int j = 0; j < 8; ++j) v[j] = (short)f2bf(Wm[(size_t)(kb + j) * 256 + col]);
    *(bf16x8*)(out + (size_t)q * 8) = v;
}

__global__ void k_pre(const float* __restrict__ x, ushort* __restrict__ xb,
                      const float* __restrict__ cls, ushort* __restrict__ h0,
                      const float* __restrict__ W_in, ushort* __restrict__ wf_in,
                      const float* __restrict__ W_gat, ushort* __restrict__ wf_gat,
                      const int* __restrict__ batch, int* lo, int* hi,
                      int* deg, int* cursor, int N, int B, int n_new) {
    int bid = blockIdx.x, t = threadIdx.x;
    const int nb_cvt  = (N * 128 / 4 + 255) / 256;
    const int nb_init = (n_new + 255) / 256;
    const int nb_bnd  = (N + 255) / 256;
    const int nb_cls  = (B * HID / 4 + 255) / 256;
    const int nb_fin  = (4 * 1024 + 255) / 256;

    if (bid < nb_cvt) {
        int i = bid * 256 + t;
        int n4 = N * 128 / 4;
        if (i < n4) {
            float4 v = ((const float4*)x)[i];
            ushort4 o;
            o.x = f2bf(v.x); o.y = f2bf(v.y); o.z = f2bf(v.z); o.w = f2bf(v.w);
            ((ushort4*)xb)[i] = o;
        }
        return;
    }
    bid -= nb_cvt;
    if (bid < nb_init) {
        int i = bid * 256 + t;
        if (i < n_new) { deg[i] = 0; cursor[i] = 0; }
        return;
    }
    bid -= nb_init;
    if (bid < nb_bnd) {
        int i = bid * 256 + t;
        if (i < N) {
            int b = batch[i];
            if (i == 0 || batch[i - 1] != b) lo[b] = i;
            if (i == N - 1 || batch[i + 1] != b) hi[b] = i + 1;
        }
        return;
    }
    bid -= nb_bnd;
    if (bid < nb_cls) {
        int i = bid * 256 + t;
        if (i < B * HID / 4) {
            int ch = (i & 63) * 4;
            ushort4 o;
            o.x = f2bf(cls[ch]); o.y = f2bf(cls[ch + 1]);
            o.z = f2bf(cls[ch + 2]); o.w = f2bf(cls[ch + 3]);
            ((ushort4*)h0)[i] = o;
        }
        return;
    }
    bid -= nb_cls;
    if (bid < nb_fin) {
        frag_task(W_in, wf_in, 4, 1, bid * 256 + t);
        return;
    }
    bid -= nb_fin;
    frag_task(W_gat, wf_gat, 8, 3, bid * 256 + t);
}

// ---------------- CSR build ----------------

__global__ void k_count(const int* __restrict__ dst0, int* deg, int E, int B) {
    int e = blockIdx.x * blockDim.x + threadIdx.x;
    if (e < E) atomicAdd(&deg[dst0[e] + B], 1);
}

// exclusive scan, single block of 1024, shfl-based
__global__ void k_scan(const int* __restrict__ deg, int* __restrict__ off, int n) {
    __shared__ int wsum[16];
    __shared__ int carry_s;
    int t = threadIdx.x, w = t >> 6, lane = t & 63;
    if (t == 0) { carry_s = 0; off[0] = 0; }
    __syncthreads();
    for (int base = 0; base < n; base += 1024) {
        int i = base + t;
        int v = (i < n) ? deg[i] : 0;
        int x = v;
#pragma unroll
        for (int o = 1; o < 64; o <<= 1) {
            int u = __shfl_up(x, o, 64);
            if (lane >= o) x += u;
        }
        if (lane == 63) wsum[w] = x;
        __syncthreads();
        int wpre = 0, total = 0;
#pragma unroll
        for (int k = 0; k < 16; ++k) {
            int s = wsum[k];
            wpre += (k < w) ? s : 0;
            total += s;
        }
        int c = carry_s;
        if (i < n) off[i + 1] = c + wpre + x;
        __syncthreads();
        if (t == 0) carry_s = c + total;
        __syncthreads();
    }
}

__global__ void k_fill(const int* __restrict__ src0, const int* __restrict__ dst0,
                       const int* __restrict__ off, int* cursor, int* __restrict__ csr,
                       int E, int B) {
    int e = blockIdx.x * blockDim.x + threadIdx.x;
    if (e < E) {
        int d = dst0[e] + B;
        int p = atomicAdd(&cursor[d], 1);
        csr[off[d] + p] = src0[e] + B;
    }
}

// ---------------- MFMA GEMM: out[row][0:256] = A[row][0:K] @ W ----------------
// block = 128 (2 waves), 32 rows/wave, 64 rows/block, no LDS.

template <int KS, bool ATT, bool BIAS>
__global__ __launch_bounds__(128, 1) void k_mgemm(
    const ushort* __restrict__ A, const ushort* __restrict__ Wf,
    const float* __restrict__ bias, ushort* __restrict__ outb,
    const float* __restrict__ att_s, const float* __restrict__ att_d,
    float* __restrict__ al_s, float* __restrict__ al_d, int rows)
{
    constexpr int K = KS * 32;
    int lane = threadIdx.x & 63, w = threadIdx.x >> 6;
    int rbase = blockIdx.x * 64 + w * 32;
    int arow0 = rbase + (lane & 15);
    int kofs = (lane >> 4) << 3;

    f32x4 acc[2][16];
#pragma unroll
    for (int mf = 0; mf < 2; ++mf)
#pragma unroll
        for (int nf = 0; nf < 16; ++nf) acc[mf][nf] = (f32x4){0.f, 0.f, 0.f, 0.f};

    const ushort* a0p = A + (size_t)arow0 * K + kofs;
    const ushort* a1p = a0p + (size_t)16 * K;
    bool g0 = arow0 < rows, g1 = (arow0 + 16) < rows;

#pragma unroll
    for (int kk = 0; kk < KS; ++kk) {
        bf16x8 af0 = {0, 0, 0, 0, 0, 0, 0, 0}, af1 = {0, 0, 0, 0, 0, 0, 0, 0};
        if (g0) af0 = *(const bf16x8*)(a0p + kk * 32);
        if (g1) af1 = *(const bf16x8*)(a1p + kk * 32);
        const bf16x8* wp = ((const bf16x8*)Wf) + (size_t)(kk * 16) * 64 + lane;
#pragma unroll
        for (int nf = 0; nf < 16; ++nf) {
            bf16x8 bv = wp[nf * 64];
            acc[0][nf] = __builtin_amdgcn_mfma_f32_16x16x32_bf16(af0, bv, acc[0][nf], 0, 0, 0);
            acc[1][nf] = __builtin_amdgcn_mfma_f32_16x16x32_bf16(af1, bv, acc[1][nf], 0, 0, 0);
        }
    }

    int rg = (lane >> 4) * 4;
    int c0 = lane & 15;
    float bv[16];
    if (BIAS) {
#pragma unroll
        for (int nf = 0; nf < 16; ++nf) bv[nf] = bias[nf * 16 + c0];
    }
#pragma unroll
    for (int mf = 0; mf < 2; ++mf)
#pragma unroll
        for (int r = 0; r < 4; ++r) {
            int row = rbase + mf * 16 + rg + r;
            if (row < rows) {
#pragma unroll
                for (int nf = 0; nf < 16; ++nf) {
                    float v = acc[mf][nf][r];
                    if (BIAS) v += bv[nf];
                    outb[(size_t)row * HID + nf * 16 + c0] = f2bf(v);
                }
            }
        }

    if (ATT) {
        float as[16], ad[16];
#pragma unroll
        for (int nf = 0; nf < 16; ++nf) {
            as[nf] = att_s[nf * 16 + c0];
            ad[nf] = att_d[nf * 16 + c0];
        }
#pragma unroll
        for (int mf = 0; mf < 2; ++mf)
#pragma unroll
            for (int r = 0; r < 4; ++r) {
                float ps[4] = {0.f, 0.f, 0.f, 0.f}, pd[4] = {0.f, 0.f, 0.f, 0.f};
#pragma unroll
                for (int nf = 0; nf < 16; ++nf) {
                    float v = acc[mf][nf][r];
                    ps[nf >> 2] += v * as[nf];
                    pd[nf >> 2] += v * ad[nf];
                }
#pragma unroll
                for (int o = 1; o < 16; o <<= 1) {
#pragma unroll
                    for (int h = 0; h < 4; ++h) {
                        ps[h] += __shfl_xor(ps[h], o, 64);
                        pd[h] += __shfl_xor(pd[h], o, 64);
                    }
                }
                int row = rbase + mf * 16 + rg + r;
                if (c0 == 0 && row < rows) {
                    float4 vs, vd;
                    vs.x = ps[0]; vs.y = ps[1]; vs.z = ps[2]; vs.w = ps[3];
                    vd.x = pd[0]; vd.y = pd[1]; vd.z = pd[2]; vd.w = pd[3];
                    *(float4*)(al_s + row * 4) = vs;
                    *(float4*)(al_d + row * 4) = vd;
                }
            }
    }
}

// ---------------- GAT aggregation + bias + residual + LayerNorm ----------------
// SINGLE PASS: softmax without max-subtraction (logits are O(+-7), exp fits fp32).
// acc += exp(v)*x and den += exp(v) in one edge sweep; divide at the end.
// One wave per node. lane = es(2 edge slots) x cg(32 ch-groups of 8 ch); head=cg>>3.

__global__ __launch_bounds__(256, 8) void k_agg(
    const ushort* __restrict__ hb, const ushort* __restrict__ xs,
    const float* __restrict__ al_s, const float* __restrict__ al_d,
    const int* __restrict__ off, const int* __restrict__ csr,
    const int* __restrict__ batch, const int* __restrict__ lo,
    const int* __restrict__ hi,
    const float* __restrict__ b_gat, const float* __restrict__ ln_g,
    const float* __restrict__ ln_b,
    ushort* __restrict__ h_out, int n_new, int B)
{
    int t = threadIdx.x, w = t >> 6, lane = t & 63;
    int n = blockIdx.x * 4 + w;
    if (n >= n_new) return;
    int es = lane >> 5, cg = lane & 31, head = cg >> 3;

    int gbeg = 0, gdeg = 0, cbeg = 0, cdeg = 0;
    if (n >= B) { gbeg = off[n]; gdeg = off[n + 1] - gbeg; cdeg = 1; }
    else { cbeg = lo[n]; cdeg = hi[n] - cbeg; }
    int cnt = gdeg + cdeg + 1;
    int clssrc = (n >= B) ? batch[n - B] : 0;

    float ald_h = al_d[n * 4 + head];

    float acc[8] = {0.f, 0.f, 0.f, 0.f, 0.f, 0.f, 0.f, 0.f};
    float den = 0.f;

#pragma unroll 4
    for (int eb = 0; eb < cnt; eb += 2) {
        int e = eb + es;
        if (e < cnt) {
            int src;
            if (e < gdeg) src = csr[gbeg + e];
            else if (e < gdeg + cdeg) src = (n >= B) ? clssrc : (B + cbeg + (e - gdeg));
            else src = n;
            float vh = al_s[src * 4 + head] + ald_h;
            vh = vh > 0.f ? vh : NEG * vh;
            float a = __expf(vh);
            den += a;
            bf16x8 xv = *((const bf16x8*)(xs + (size_t)src * HID) + cg);
#pragma unroll
            for (int j = 0; j < 8; ++j) acc[j] += a * bf2f((unsigned short)xv[j]);
        }
    }

    // reduce across the two edge slots (xor bit 5)
#pragma unroll
    for (int j = 0; j < 8; ++j) acc[j] += __shfl_xor(acc[j], 32, 64);
    den += __shfl_xor(den, 32, 64);
    float inv = 1.f / (den + 1e-16f);

    // residual + bias
    bf16x8 hv = *((const bf16x8*)(hb + (size_t)n * HID) + cg);
    const float4* bgp = (const float4*)(b_gat + cg * 8);
    float4 bg0 = bgp[0], bg1 = bgp[1];
    float bg[8] = {bg0.x, bg0.y, bg0.z, bg0.w, bg1.x, bg1.y, bg1.z, bg1.w};
    float r[8];
#pragma unroll
    for (int j = 0; j < 8; ++j)
        r[j] = bf2f((unsigned short)hv[j]) + acc[j] * inv + bg[j];

    // LayerNorm: butterfly over the 32 channel groups (bits 0..4)
    float ss = 0.f;
#pragma unroll
    for (int j = 0; j < 8; ++j) ss += r[j];
#pragma unroll
    for (int o = 1; o < 32; o <<= 1) ss += __shfl_xor(ss, o, 64);
    float mu = ss * (1.f / HID);
    float vv = 0.f;
#pragma unroll
    for (int j = 0; j < 8; ++j) { r[j] -= mu; vv += r[j] * r[j]; }
#pragma unroll
    for (int o = 1; o < 32; o <<= 1) vv += __shfl_xor(vv, o, 64);
    float rs = rsqrtf(vv * (1.f / HID) + EPS);

    if (es == 0) {
        const float4* gp = (const float4*)(ln_g + cg * 8);
        const float4* bp = (const float4*)(ln_b + cg * 8);
        float4 g0 = gp[0], g1 = gp[1];
        float4 lb0 = bp[0], lb1 = bp[1];
        float gg[8] = {g0.x, g0.y, g0.z, g0.w, g1.x, g1.y, g1.z, g1.w};
        float bb[8] = {lb0.x, lb0.y, lb0.z, lb0.w, lb1.x, lb1.y, lb1.z, lb1.w};
        bf16x8 o8;
#pragma unroll
        for (int j = 0; j < 8; ++j) o8[j] = (short)f2bf(r[j] * rs * gg[j] + bb[j]);
        *((bf16x8*)(h_out + (size_t)n * HID) + cg) = o8;
    }
}

// ---------------- output projection (B x 256 @ 256 x 256) ----------------

__global__ __launch_bounds__(256) void k_out(
    const ushort* __restrict__ h, const float* __restrict__ Wm,
    const float* __restrict__ bias, float* __restrict__ z)
{
    __shared__ float hs[HID];
    int b = blockIdx.x, t = threadIdx.x;
    hs[t] = bf2f(h[(size_t)b * HID + t]);
    __syncthreads();
    float acc = bias[t];
#pragma unroll 8
    for (int k = 0; k < HID; ++k) acc += hs[k] * Wm[k * HID + t];
    z[(size_t)b * HID + t] = acc;
}

// ---------------- launch ----------------

extern "C" void kernel_launch(void* const* d_in, const int* in_sizes, int n_in,
                              void* d_out, int out_size, void* d_ws, size_t ws_size,
                              hipStream_t stream) {
    const float* x      = (const float*)d_in[0];
    const int*   ei     = (const int*)d_in[1];
    const int*   batch  = (const int*)d_in[2];
    const float* W_in   = (const float*)d_in[3];
    const float* b_in   = (const float*)d_in[4];
    const float* cls    = (const float*)d_in[5];
    const float* W_gat  = (const float*)d_in[6];
    const float* att_s  = (const float*)d_in[7];
    const float* att_d  = (const float*)d_in[8];
    const float* b_gat  = (const float*)d_in[9];
    const float* ln_g   = (const float*)d_in[10];
    const float* ln_b   = (const float*)d_in[11];
    const float* W_out  = (const float*)d_in[12];
    const float* b_out  = (const float*)d_in[13];

    const int N = in_sizes[0] / 128;
    const int E = in_sizes[1] / 2;
    const int B = 64;
    const int n_new = N + B;
    const int* src0 = ei;
    const int* dst0 = ei + E;

    char* p = (char*)d_ws;
    auto alloc = [&](size_t bytes) -> void* {
        void* r = (void*)p;
        p += (bytes + 255) & ~(size_t)255;
        return r;
    };
    int*    off    = (int*)alloc((size_t)(n_new + 1) * 4);
    int*    deg    = (int*)alloc((size_t)n_new * 4);
    int*    cursor = (int*)alloc((size_t)n_new * 4);
    int*    csr    = (int*)alloc((size_t)E * 4);
    int*    lo     = (int*)alloc((size_t)B * 4);
    int*    hi     = (int*)alloc((size_t)B * 4);
    ushort* xb     = (ushort*)alloc((size_t)N * 128 * 2);
    ushort* h0b    = (ushort*)alloc((size_t)n_new * HID * 2);
    ushort* h1b    = (ushort*)alloc((size_t)n_new * HID * 2);
    ushort* xsb    = (ushort*)alloc((size_t)n_new * HID * 2);
    float*  als    = (float*)alloc((size_t)n_new * 4 * 4);
    float*  aldv   = (float*)alloc((size_t)n_new * 4 * 4);
    ushort* wf_in  = (ushort*)alloc((size_t)4 * 1024 * 8 * 2);
    ushort* wf_gat = (ushort*)alloc((size_t)3 * 8 * 1024 * 8 * 2);

    const int nb_pre = (N * 128 / 4 + 255) / 256 + (n_new + 255) / 256 +
                       (N + 255) / 256 + (B * HID / 4 + 255) / 256 +
                       (4 * 1024 + 255) / 256 + (3 * 8 * 1024 + 255) / 256;
    k_pre<<<nb_pre, 256, 0, stream>>>(x, xb, cls, h0b, W_in, wf_in, W_gat, wf_gat,
                                      batch, lo, hi, deg, cursor, N, B, n_new);
    k_count<<<(E + 255) / 256, 256, 0, stream>>>(dst0, deg, E, B);
    k_scan<<<1, 1024, 0, stream>>>(deg, off, n_new);
    k_fill<<<(E + 255) / 256, 256, 0, stream>>>(src0, dst0, off, cursor, csr, E, B);

    k_mgemm<4, false, true><<<(N + 63) / 64, 128, 0, stream>>>(
        xb, wf_in, b_in, h0b + (size_t)B * HID, nullptr, nullptr, nullptr, nullptr, N);

    ushort* cur = h0b;
    ushort* nxt = h1b;
    for (int l = 0; l < 3; ++l) {
        k_mgemm<8, true, false><<<(n_new + 63) / 64, 128, 0, stream>>>(
            cur, wf_gat + (size_t)l * 65536, nullptr, xsb,
            att_s + l * HID, att_d + l * HID, als, aldv, n_new);
        k_agg<<<(n_new + 3) / 4, 256, 0, stream>>>(
            cur, xsb, als, aldv, off, csr, batch, lo, hi,
            b_gat + l * HID, ln_g + l * HID, ln_b + l * HID, nxt, n_new, B);
        ushort* tmp = cur; cur = nxt; nxt = tmp;
    }
    k_out<<<B, 256, 0, stream>>>(cur, W_out, b_out, (float*)d_out);
}

// Round 6
// 378.099 us; speedup vs baseline: 1.0047x; 1.0047x over previous
//
#include <hip/hip_runtime.h>
#include <hip/hip_bf16.h>

constexpr int HID = 256;
constexpr float NEG = 0.2f;
constexpr float EPS = 1e-5f;

typedef __attribute__((ext_vector_type(8))) short bf16x8;
typedef __attribute__((ext_vector_type(4))) float f32x4;

static __device__ __forceinline__ unsigned short f2bf(float f) {
    unsigned u = __builtin_bit_cast(unsigned, f);
    u += 0x7fffu + ((u >> 16) & 1u);
    return (unsigned short)(u >> 16);
}
static __device__ __forceinline__ float bf2f(unsigned short h) {
    return __builtin_bit_cast(float, ((unsigned)h) << 16);
}
static __device__ __forceinline__ float elk(float v) {
    v = v > 0.f ? v : NEG * v;
    return __expf(v);
}

// ---------------- fused preprocessing ----------------
// NOTE: lo/hi written ONLY by the bounds task (each graph id exactly once);
// zero-initializing them here would race (round-4 bug).

__device__ __forceinline__ void frag_task(const float* __restrict__ W,
                                          ushort* __restrict__ out,
                                          int KS, int nmat, int q) {
    int per = KS * 1024;
    if (q >= per * nmat) return;
    int mat = q / per, r = q - mat * per;
    int l = r & 63, nf = (r >> 6) & 15, kk = r >> 10;
    const float* Wm = W + (size_t)mat * KS * 32 * 256;
    int kb = kk * 32 + ((l >> 4) << 3);
    int col = nf * 16 + (l & 15);
    bf16x8 v;
#pragma unroll
    for (int j = 0; j < 8; ++j) v[j] = (short)f2bf(Wm[(size_t)(kb + j) * 256 + col]);
    *(bf16x8*)(out + (size_t)q * 8) = v;
}

__global__ void k_pre(const float* __restrict__ x, ushort* __restrict__ xb,
                      const float* __restrict__ cls, ushort* __restrict__ h0,
                      const float* __restrict__ W_in, ushort* __restrict__ wf_in,
                      const float* __restrict__ W_gat, ushort* __restrict__ wf_gat,
                      const int* __restrict__ batch, int* lo, int* hi,
                      int* deg, int* cursor, int N, int B, int n_new) {
    int bid = blockIdx.x, t = threadIdx.x;
    const int nb_cvt  = (N * 128 / 4 + 255) / 256;
    const int nb_init = (n_new + 255) / 256;
    const int nb_bnd  = (N + 255) / 256;
    const int nb_cls  = (B * HID / 4 + 255) / 256;
    const int nb_fin  = (4 * 1024 + 255) / 256;

    if (bid < nb_cvt) {
        int i = bid * 256 + t;
        int n4 = N * 128 / 4;
        if (i < n4) {
            float4 v = ((const float4*)x)[i];
            ushort4 o;
            o.x = f2bf(v.x); o.y = f2bf(v.y); o.z = f2bf(v.z); o.w = f2bf(v.w);
            ((ushort4*)xb)[i] = o;
        }
        return;
    }
    bid -= nb_cvt;
    if (bid < nb_init) {
        int i = bid * 256 + t;
        if (i < n_new) { deg[i] = 0; cursor[i] = 0; }
        return;
    }
    bid -= nb_init;
    if (bid < nb_bnd) {
        int i = bid * 256 + t;
        if (i < N) {
            int b = batch[i];
            if (i == 0 || batch[i - 1] != b) lo[b] = i;
            if (i == N - 1 || batch[i + 1] != b) hi[b] = i + 1;
        }
        return;
    }
    bid -= nb_bnd;
    if (bid < nb_cls) {
        int i = bid * 256 + t;
        if (i < B * HID / 4) {
            int ch = (i & 63) * 4;
            ushort4 o;
            o.x = f2bf(cls[ch]); o.y = f2bf(cls[ch + 1]);
            o.z = f2bf(cls[ch + 2]); o.w = f2bf(cls[ch + 3]);
            ((ushort4*)h0)[i] = o;
        }
        return;
    }
    bid -= nb_cls;
    if (bid < nb_fin) {
        frag_task(W_in, wf_in, 4, 1, bid * 256 + t);
        return;
    }
    bid -= nb_fin;
    frag_task(W_gat, wf_gat, 8, 3, bid * 256 + t);
}

// ---------------- CSR build ----------------

__global__ void k_count(const int* __restrict__ dst0, int* deg, int E, int B) {
    int e = blockIdx.x * blockDim.x + threadIdx.x;
    if (e < E) atomicAdd(&deg[dst0[e] + B], 1);
}

__global__ void k_scan(const int* __restrict__ deg, int* __restrict__ off, int n) {
    __shared__ int wsum[16];
    __shared__ int carry_s;
    int t = threadIdx.x, w = t >> 6, lane = t & 63;
    if (t == 0) { carry_s = 0; off[0] = 0; }
    __syncthreads();
    for (int base = 0; base < n; base += 1024) {
        int i = base + t;
        int v = (i < n) ? deg[i] : 0;
        int x = v;
#pragma unroll
        for (int o = 1; o < 64; o <<= 1) {
            int u = __shfl_up(x, o, 64);
            if (lane >= o) x += u;
        }
        if (lane == 63) wsum[w] = x;
        __syncthreads();
        int wpre = 0, total = 0;
#pragma unroll
        for (int k = 0; k < 16; ++k) {
            int s = wsum[k];
            wpre += (k < w) ? s : 0;
            total += s;
        }
        int c = carry_s;
        if (i < n) off[i + 1] = c + wpre + x;
        __syncthreads();
        if (t == 0) carry_s = c + total;
        __syncthreads();
    }
}

__global__ void k_fill(const int* __restrict__ src0, const int* __restrict__ dst0,
                       const int* __restrict__ off, int* cursor,
                       int* __restrict__ csr, int* __restrict__ csrd, int E, int B) {
    int e = blockIdx.x * blockDim.x + threadIdx.x;
    if (e < E) {
        int d = dst0[e] + B;
        int p = atomicAdd(&cursor[d], 1);
        int q = off[d] + p;
        csr[q] = src0[e] + B;
        csrd[q] = d;
    }
}

// ---------------- per-edge attention weights (per layer) ----------------
// a4[q][h] = exp(leaky(al_s[csr[q]][h] + al_d[csrd[q]][h])) for CSR slots;
// aself4[n][h] = self-loop weight; acls4[n][h] = CLS->node edge weight (n>=B).
// Edge-parallel + node-parallel range partition; all gathers hit the 321 KB
// al_s/al_d arrays (L2-resident), fully latency-tolerant.

__global__ void k_alpha(const int* __restrict__ csr, const int* __restrict__ csrd,
                        const float* __restrict__ als, const float* __restrict__ ald,
                        const int* __restrict__ batch,
                        float* __restrict__ a4, float* __restrict__ acls,
                        float* __restrict__ aself, int E, int n_new, int B) {
    int i = blockIdx.x * 256 + threadIdx.x;
    if (i < E) {
        int s = csr[i], d = csrd[i];
        float4 s4 = ((const float4*)als)[s];
        float4 d4 = ((const float4*)ald)[d];
        float4 o;
        o.x = elk(s4.x + d4.x);
        o.y = elk(s4.y + d4.y);
        o.z = elk(s4.z + d4.z);
        o.w = elk(s4.w + d4.w);
        ((float4*)a4)[i] = o;
        return;
    }
    int n = i - E;
    if (n < n_new) {
        float4 d4 = ((const float4*)ald)[n];
        float4 s4 = ((const float4*)als)[n];
        float4 o;
        o.x = elk(s4.x + d4.x);
        o.y = elk(s4.y + d4.y);
        o.z = elk(s4.z + d4.z);
        o.w = elk(s4.w + d4.w);
        ((float4*)aself)[n] = o;
        if (n >= B) {
            float4 c4 = ((const float4*)als)[batch[n - B]];
            float4 p;
            p.x = elk(c4.x + d4.x);
            p.y = elk(c4.y + d4.y);
            p.z = elk(c4.z + d4.z);
            p.w = elk(c4.w + d4.w);
            ((float4*)acls)[n] = p;
        }
    }
}

// ---------------- MFMA GEMM: out[row][0:256] = A[row][0:K] @ W ----------------

template <int KS, bool ATT, bool BIAS>
__global__ __launch_bounds__(128, 1) void k_mgemm(
    const ushort* __restrict__ A, const ushort* __restrict__ Wf,
    const float* __restrict__ bias, ushort* __restrict__ outb,
    const float* __restrict__ att_s, const float* __restrict__ att_d,
    float* __restrict__ al_s, float* __restrict__ al_d, int rows)
{
    constexpr int K = KS * 32;
    int lane = threadIdx.x & 63, w = threadIdx.x >> 6;
    int rbase = blockIdx.x * 64 + w * 32;
    int arow0 = rbase + (lane & 15);
    int kofs = (lane >> 4) << 3;

    f32x4 acc[2][16];
#pragma unroll
    for (int mf = 0; mf < 2; ++mf)
#pragma unroll
        for (int nf = 0; nf < 16; ++nf) acc[mf][nf] = (f32x4){0.f, 0.f, 0.f, 0.f};

    const ushort* a0p = A + (size_t)arow0 * K + kofs;
    const ushort* a1p = a0p + (size_t)16 * K;
    bool g0 = arow0 < rows, g1 = (arow0 + 16) < rows;

#pragma unroll
    for (int kk = 0; kk < KS; ++kk) {
        bf16x8 af0 = {0, 0, 0, 0, 0, 0, 0, 0}, af1 = {0, 0, 0, 0, 0, 0, 0, 0};
        if (g0) af0 = *(const bf16x8*)(a0p + kk * 32);
        if (g1) af1 = *(const bf16x8*)(a1p + kk * 32);
        const bf16x8* wp = ((const bf16x8*)Wf) + (size_t)(kk * 16) * 64 + lane;
#pragma unroll
        for (int nf = 0; nf < 16; ++nf) {
            bf16x8 bv = wp[nf * 64];
            acc[0][nf] = __builtin_amdgcn_mfma_f32_16x16x32_bf16(af0, bv, acc[0][nf], 0, 0, 0);
            acc[1][nf] = __builtin_amdgcn_mfma_f32_16x16x32_bf16(af1, bv, acc[1][nf], 0, 0, 0);
        }
    }

    int rg = (lane >> 4) * 4;
    int c0 = lane & 15;
    float bv[16];
    if (BIAS) {
#pragma unroll
        for (int nf = 0; nf < 16; ++nf) bv[nf] = bias[nf * 16 + c0];
    }
#pragma unroll
    for (int mf = 0; mf < 2; ++mf)
#pragma unroll
        for (int r = 0; r < 4; ++r) {
            int row = rbase + mf * 16 + rg + r;
            if (row < rows) {
#pragma unroll
                for (int nf = 0; nf < 16; ++nf) {
                    float v = acc[mf][nf][r];
                    if (BIAS) v += bv[nf];
                    outb[(size_t)row * HID + nf * 16 + c0] = f2bf(v);
                }
            }
        }

    if (ATT) {
        float as[16], ad[16];
#pragma unroll
        for (int nf = 0; nf < 16; ++nf) {
            as[nf] = att_s[nf * 16 + c0];
            ad[nf] = att_d[nf * 16 + c0];
        }
#pragma unroll
        for (int mf = 0; mf < 2; ++mf)
#pragma unroll
            for (int r = 0; r < 4; ++r) {
                float ps[4] = {0.f, 0.f, 0.f, 0.f}, pd[4] = {0.f, 0.f, 0.f, 0.f};
#pragma unroll
                for (int nf = 0; nf < 16; ++nf) {
                    float v = acc[mf][nf][r];
                    ps[nf >> 2] += v * as[nf];
                    pd[nf >> 2] += v * ad[nf];
                }
#pragma unroll
                for (int o = 1; o < 16; o <<= 1) {
#pragma unroll
                    for (int h = 0; h < 4; ++h) {
                        ps[h] += __shfl_xor(ps[h], o, 64);
                        pd[h] += __shfl_xor(pd[h], o, 64);
                    }
                }
                int row = rbase + mf * 16 + rg + r;
                if (c0 == 0 && row < rows) {
                    float4 vs, vd;
                    vs.x = ps[0]; vs.y = ps[1]; vs.z = ps[2]; vs.w = ps[3];
                    vd.x = pd[0]; vd.y = pd[1]; vd.z = pd[2]; vd.w = pd[3];
                    *(float4*)(al_s + row * 4) = vs;
                    *(float4*)(al_d + row * 4) = vd;
                }
            }
    }
}

// ---------------- GAT aggregation + bias + residual + LayerNorm ----------------
// Hot loop per graph edge: one sequential a4 dword + ONE random 16B xs load +
// 8 FMA. All attention weights precomputed (k_alpha); CLS/self terms added
// outside the loop. unroll 8 -> 16 row-gathers in flight per wave.
// One wave per node; lane = es(2) x cg(32 groups of 8 ch); head = cg>>3.

__global__ __launch_bounds__(256, 8) void k_agg(
    const ushort* __restrict__ hb, const ushort* __restrict__ xs,
    const float* __restrict__ a4, const float* __restrict__ acls,
    const float* __restrict__ aself,
    const float* __restrict__ als, const float* __restrict__ ald,
    const int* __restrict__ off, const int* __restrict__ csr,
    const int* __restrict__ batch, const int* __restrict__ lo,
    const int* __restrict__ hi,
    const float* __restrict__ b_gat, const float* __restrict__ ln_g,
    const float* __restrict__ ln_b,
    ushort* __restrict__ h_out, int n_new, int B)
{
    int t = threadIdx.x, w = t >> 6, lane = t & 63;
    int n = blockIdx.x * 4 + w;
    if (n >= n_new) return;
    int es = lane >> 5, cg = lane & 31, head = cg >> 3;

    float acc[8] = {0.f, 0.f, 0.f, 0.f, 0.f, 0.f, 0.f, 0.f};
    float den = 0.f;

    if (n >= B) {
        int gbeg = off[n], gdeg = off[n + 1] - gbeg;
        int clssrc = batch[n - B];
        bf16x8 xcls  = *((const bf16x8*)(xs + (size_t)clssrc * HID) + cg);
        bf16x8 xself = *((const bf16x8*)(xs + (size_t)n * HID) + cg);
        float acl = acls[n * 4 + head];
        float asf = aself[n * 4 + head];

#pragma unroll 8
        for (int eb = 0; eb < gdeg; eb += 2) {
            int e = eb + es;
            if (e < gdeg) {
                int q = gbeg + e;
                int src = csr[q];
                float a = a4[(size_t)q * 4 + head];
                bf16x8 xv = *((const bf16x8*)(xs + (size_t)src * HID) + cg);
                den += a;
#pragma unroll
                for (int j = 0; j < 8; ++j) acc[j] += a * bf2f((unsigned short)xv[j]);
            }
        }
        if (es == 0) {
            den += acl + asf;
#pragma unroll
            for (int j = 0; j < 8; ++j)
                acc[j] += acl * bf2f((unsigned short)xcls[j]) +
                          asf * bf2f((unsigned short)xself[j]);
        }
    } else {
        // CLS node: sources are the contiguous node range [lo,hi) of its graph.
        int cbeg = lo[n], cdeg = hi[n] - cbeg;
        float ald_h = ald[n * 4 + head];
        bf16x8 xself = *((const bf16x8*)(xs + (size_t)n * HID) + cg);
        float asf = aself[n * 4 + head];

#pragma unroll 4
        for (int eb = 0; eb < cdeg; eb += 2) {
            int e = eb + es;
            if (e < cdeg) {
                int src = B + cbeg + e;
                float a = elk(als[src * 4 + head] + ald_h);
                bf16x8 xv = *((const bf16x8*)(xs + (size_t)src * HID) + cg);
                den += a;
#pragma unroll
                for (int j = 0; j < 8; ++j) acc[j] += a * bf2f((unsigned short)xv[j]);
            }
        }
        if (es == 0) {
            den += asf;
#pragma unroll
            for (int j = 0; j < 8; ++j) acc[j] += asf * bf2f((unsigned short)xself[j]);
        }
    }

    // reduce across the two edge slots (xor bit 5)
#pragma unroll
    for (int j = 0; j < 8; ++j) acc[j] += __shfl_xor(acc[j], 32, 64);
    den += __shfl_xor(den, 32, 64);
    float inv = 1.f / (den + 1e-16f);

    // residual + bias
    bf16x8 hv = *((const bf16x8*)(hb + (size_t)n * HID) + cg);
    const float4* bgp = (const float4*)(b_gat + cg * 8);
    float4 bg0 = bgp[0], bg1 = bgp[1];
    float bg[8] = {bg0.x, bg0.y, bg0.z, bg0.w, bg1.x, bg1.y, bg1.z, bg1.w};
    float r[8];
#pragma unroll
    for (int j = 0; j < 8; ++j)
        r[j] = bf2f((unsigned short)hv[j]) + acc[j] * inv + bg[j];

    // LayerNorm: butterfly over the 32 channel groups (bits 0..4)
    float ss = 0.f;
#pragma unroll
    for (int j = 0; j < 8; ++j) ss += r[j];
#pragma unroll
    for (int o = 1; o < 32; o <<= 1) ss += __shfl_xor(ss, o, 64);
    float mu = ss * (1.f / HID);
    float vv = 0.f;
#pragma unroll
    for (int j = 0; j < 8; ++j) { r[j] -= mu; vv += r[j] * r[j]; }
#pragma unroll
    for (int o = 1; o < 32; o <<= 1) vv += __shfl_xor(vv, o, 64);
    float rs = rsqrtf(vv * (1.f / HID) + EPS);

    if (es == 0) {
        const float4* gp = (const float4*)(ln_g + cg * 8);
        const float4* bp = (const float4*)(ln_b + cg * 8);
        float4 g0 = gp[0], g1 = gp[1];
        float4 lb0 = bp[0], lb1 = bp[1];
        float gg[8] = {g0.x, g0.y, g0.z, g0.w, g1.x, g1.y, g1.z, g1.w};
        float bb[8] = {lb0.x, lb0.y, lb0.z, lb0.w, lb1.x, lb1.y, lb1.z, lb1.w};
        bf16x8 o8;
#pragma unroll
        for (int j = 0; j < 8; ++j) o8[j] = (short)f2bf(r[j] * rs * gg[j] + bb[j]);
        *((bf16x8*)(h_out + (size_t)n * HID) + cg) = o8;
    }
}

// ---------------- output projection (B x 256 @ 256 x 256) ----------------

__global__ __launch_bounds__(256) void k_out(
    const ushort* __restrict__ h, const float* __restrict__ Wm,
    const float* __restrict__ bias, float* __restrict__ z)
{
    __shared__ float hs[HID];
    int b = blockIdx.x, t = threadIdx.x;
    hs[t] = bf2f(h[(size_t)b * HID + t]);
    __syncthreads();
    float acc = bias[t];
#pragma unroll 8
    for (int k = 0; k < HID; ++k) acc += hs[k] * Wm[k * HID + t];
    z[(size_t)b * HID + t] = acc;
}

// ---------------- launch ----------------

extern "C" void kernel_launch(void* const* d_in, const int* in_sizes, int n_in,
                              void* d_out, int out_size, void* d_ws, size_t ws_size,
                              hipStream_t stream) {
    const float* x      = (const float*)d_in[0];
    const int*   ei     = (const int*)d_in[1];
    const int*   batch  = (const int*)d_in[2];
    const float* W_in   = (const float*)d_in[3];
    const float* b_in   = (const float*)d_in[4];
    const float* cls    = (const float*)d_in[5];
    const float* W_gat  = (const float*)d_in[6];
    const float* att_s  = (const float*)d_in[7];
    const float* att_d  = (const float*)d_in[8];
    const float* b_gat  = (const float*)d_in[9];
    const float* ln_g   = (const float*)d_in[10];
    const float* ln_b   = (const float*)d_in[11];
    const float* W_out  = (const float*)d_in[12];
    const float* b_out  = (const float*)d_in[13];

    const int N = in_sizes[0] / 128;
    const int E = in_sizes[1] / 2;
    const int B = 64;
    const int n_new = N + B;
    const int* src0 = ei;
    const int* dst0 = ei + E;

    char* p = (char*)d_ws;
    auto alloc = [&](size_t bytes) -> void* {
        void* r = (void*)p;
        p += (bytes + 255) & ~(size_t)255;
        return r;
    };
    int*    off    = (int*)alloc((size_t)(n_new + 1) * 4);
    int*    deg    = (int*)alloc((size_t)n_new * 4);
    int*    cursor = (int*)alloc((size_t)n_new * 4);
    int*    csr    = (int*)alloc((size_t)E * 4);
    int*    csrd   = (int*)alloc((size_t)E * 4);
    int*    lo     = (int*)alloc((size_t)B * 4);
    int*    hi     = (int*)alloc((size_t)B * 4);
    ushort* xb     = (ushort*)alloc((size_t)N * 128 * 2);
    ushort* h0b    = (ushort*)alloc((size_t)n_new * HID * 2);
    ushort* h1b    = (ushort*)alloc((size_t)n_new * HID * 2);
    ushort* xsb    = (ushort*)alloc((size_t)n_new * HID * 2);
    float*  als    = (float*)alloc((size_t)n_new * 4 * 4);
    float*  aldv   = (float*)alloc((size_t)n_new * 4 * 4);
    float*  a4     = (float*)alloc((size_t)E * 4 * 4);
    float*  acls   = (float*)alloc((size_t)n_new * 4 * 4);
    float*  aselfv = (float*)alloc((size_t)n_new * 4 * 4);
    ushort* wf_in  = (ushort*)alloc((size_t)4 * 1024 * 8 * 2);
    ushort* wf_gat = (ushort*)alloc((size_t)3 * 8 * 1024 * 8 * 2);

    const int nb_pre = (N * 128 / 4 + 255) / 256 + (n_new + 255) / 256 +
                       (N + 255) / 256 + (B * HID / 4 + 255) / 256 +
                       (4 * 1024 + 255) / 256 + (3 * 8 * 1024 + 255) / 256;
    k_pre<<<nb_pre, 256, 0, stream>>>(x, xb, cls, h0b, W_in, wf_in, W_gat, wf_gat,
                                      batch, lo, hi, deg, cursor, N, B, n_new);
    k_count<<<(E + 255) / 256, 256, 0, stream>>>(dst0, deg, E, B);
    k_scan<<<1, 1024, 0, stream>>>(deg, off, n_new);
    k_fill<<<(E + 255) / 256, 256, 0, stream>>>(src0, dst0, off, cursor, csr, csrd, E, B);

    k_mgemm<4, false, true><<<(N + 63) / 64, 128, 0, stream>>>(
        xb, wf_in, b_in, h0b + (size_t)B * HID, nullptr, nullptr, nullptr, nullptr, N);

    const int nb_alpha = (E + n_new + 255) / 256;
    ushort* cur = h0b;
    ushort* nxt = h1b;
    for (int l = 0; l < 3; ++l) {
        k_mgemm<8, true, false><<<(n_new + 63) / 64, 128, 0, stream>>>(
            cur, wf_gat + (size_t)l * 65536, nullptr, xsb,
            att_s + l * HID, att_d + l * HID, als, aldv, n_new);
        k_alpha<<<nb_alpha, 256, 0, stream>>>(
            csr, csrd, als, aldv, batch, a4, acls, aselfv, E, n_new, B);
        k_agg<<<(n_new + 3) / 4, 256, 0, stream>>>(
            cur, xsb, a4, acls, aselfv, als, aldv, off, csr, batch, lo, hi,
            b_gat + l * HID, ln_g + l * HID, ln_b + l * HID, nxt, n_new, B);
        ushort* tmp = cur; cur = nxt; nxt = tmp;
    }
    k_out<<<B, 256, 0, stream>>>(cur, W_out, b_out, (float*)d_out);
}

// Round 7
// 280.988 us; speedup vs baseline: 1.3520x; 1.3456x over previous
//
#include <hip/hip_runtime.h>
#include <hip/hip_bf16.h>

constexpr int HID = 256;
constexpr float NEG = 0.2f;
constexpr float EPS = 1e-5f;

typedef __attribute__((ext_vector_type(8))) short bf16x8;
typedef __attribute__((ext_vector_type(4))) float f32x4;

static __device__ __forceinline__ unsigned short f2bf(float f) {
    unsigned u = __builtin_bit_cast(unsigned, f);
    u += 0x7fffu + ((u >> 16) & 1u);
    return (unsigned short)(u >> 16);
}
static __device__ __forceinline__ float bf2f(unsigned short h) {
    return __builtin_bit_cast(float, ((unsigned)h) << 16);
}
static __device__ __forceinline__ float elk(float v) {
    v = v > 0.f ? v : NEG * v;
    return __expf(v);
}

// ---------------- fused preprocessing ----------------
// NOTE: lo/hi written ONLY by the bounds task (each graph id exactly once);
// zero-initializing them here would race (round-4 bug). csr is -1-initialized
// here; k_fill (stream-ordered later) overwrites real slots.

__device__ __forceinline__ void frag_task(const float* __restrict__ W,
                                          ushort* __restrict__ out,
                                          int KS, int nmat, int q) {
    int per = KS * 1024;
    if (q >= per * nmat) return;
    int mat = q / per, r = q - mat * per;
    int l = r & 63, nf = (r >> 6) & 15, kk = r >> 10;
    const float* Wm = W + (size_t)mat * KS * 32 * 256;
    int kb = kk * 32 + ((l >> 4) << 3);
    int col = nf * 16 + (l & 15);
    bf16x8 v;
#pragma unroll
    for (int j = 0; j < 8; ++j) v[j] = (short)f2bf(Wm[(size_t)(kb + j) * 256 + col]);
    *(bf16x8*)(out + (size_t)q * 8) = v;
}

__global__ void k_pre(const float* __restrict__ x, ushort* __restrict__ xb,
                      const float* __restrict__ cls, ushort* __restrict__ h0,
                      const float* __restrict__ W_in, ushort* __restrict__ wf_in,
                      const float* __restrict__ W_gat, ushort* __restrict__ wf_gat,
                      const int* __restrict__ batch, int* lo, int* hi,
                      int* deg, int* cursor, int* csr,
                      int N, int B, int n_new, int EPL) {
    int bid = blockIdx.x, t = threadIdx.x;
    const int nb_cvt  = (N * 128 / 4 + 255) / 256;
    const int nb_init = (n_new + 255) / 256;
    const int nb_csr  = (EPL + 255) / 256;
    const int nb_bnd  = (N + 255) / 256;
    const int nb_cls  = (B * HID / 4 + 255) / 256;
    const int nb_fin  = (4 * 1024 + 255) / 256;

    if (bid < nb_cvt) {
        int i = bid * 256 + t;
        int n4 = N * 128 / 4;
        if (i < n4) {
            float4 v = ((const float4*)x)[i];
            ushort4 o;
            o.x = f2bf(v.x); o.y = f2bf(v.y); o.z = f2bf(v.z); o.w = f2bf(v.w);
            ((ushort4*)xb)[i] = o;
        }
        return;
    }
    bid -= nb_cvt;
    if (bid < nb_init) {
        int i = bid * 256 + t;
        if (i < n_new) { deg[i] = 0; cursor[i] = 0; }
        return;
    }
    bid -= nb_init;
    if (bid < nb_csr) {
        int i = bid * 256 + t;
        if (i < EPL) csr[i] = -1;
        return;
    }
    bid -= nb_csr;
    if (bid < nb_bnd) {
        int i = bid * 256 + t;
        if (i < N) {
            int b = batch[i];
            if (i == 0 || batch[i - 1] != b) lo[b] = i;
            if (i == N - 1 || batch[i + 1] != b) hi[b] = i + 1;
        }
        return;
    }
    bid -= nb_bnd;
    if (bid < nb_cls) {
        int i = bid * 256 + t;
        if (i < B * HID / 4) {
            int ch = (i & 63) * 4;
            ushort4 o;
            o.x = f2bf(cls[ch]); o.y = f2bf(cls[ch + 1]);
            o.z = f2bf(cls[ch + 2]); o.w = f2bf(cls[ch + 3]);
            ((ushort4*)h0)[i] = o;
        }
        return;
    }
    bid -= nb_cls;
    if (bid < nb_fin) {
        frag_task(W_in, wf_in, 4, 1, bid * 256 + t);
        return;
    }
    bid -= nb_fin;
    frag_task(W_gat, wf_gat, 8, 3, bid * 256 + t);
}

// ---------------- CSR build ----------------

__global__ void k_count(const int* __restrict__ dst0, int* deg, int E, int B) {
    int e = blockIdx.x * blockDim.x + threadIdx.x;
    if (e < E) atomicAdd(&deg[dst0[e] + B], 1);
}

// exclusive scan of PADDED degree (rounded up to multiple of 8)
__global__ void k_scan(const int* __restrict__ deg, int* __restrict__ off, int n) {
    __shared__ int wsum[16];
    __shared__ int carry_s;
    int t = threadIdx.x, w = t >> 6, lane = t & 63;
    if (t == 0) { carry_s = 0; off[0] = 0; }
    __syncthreads();
    for (int base = 0; base < n; base += 1024) {
        int i = base + t;
        int v = (i < n) ? ((deg[i] + 7) & ~7) : 0;
        int x = v;
#pragma unroll
        for (int o = 1; o < 64; o <<= 1) {
            int u = __shfl_up(x, o, 64);
            if (lane >= o) x += u;
        }
        if (lane == 63) wsum[w] = x;
        __syncthreads();
        int wpre = 0, total = 0;
#pragma unroll
        for (int k = 0; k < 16; ++k) {
            int s = wsum[k];
            wpre += (k < w) ? s : 0;
            total += s;
        }
        int c = carry_s;
        if (i < n) off[i + 1] = c + wpre + x;
        __syncthreads();
        if (t == 0) carry_s = c + total;
        __syncthreads();
    }
}

__global__ void k_fill(const int* __restrict__ src0, const int* __restrict__ dst0,
                       const int* __restrict__ off, int* cursor,
                       int* __restrict__ csr, int* __restrict__ csrd, int E, int B) {
    int e = blockIdx.x * blockDim.x + threadIdx.x;
    if (e < E) {
        int d = dst0[e] + B;
        int p = atomicAdd(&cursor[d], 1);
        int q = off[d] + p;
        csr[q] = src0[e] + B;
        csrd[q] = d;
    }
}

// ---------------- per-edge attention weights (per layer) ----------------
// a4T[h*EPL + q]   : weight of CSR slot q for head h (0 for pad slots)
// aself[n*4 + h]   : self-loop weight
// acls[n*4 + h]    : CLS->node weight (n >= B)
// aclsinT[h*nn + n]: node n -> its CLS weight (planar, n >= B)

__global__ void k_alpha(const int* __restrict__ csr, const int* __restrict__ csrd,
                        const float* __restrict__ als, const float* __restrict__ ald,
                        const int* __restrict__ batch,
                        float* __restrict__ a4T, float* __restrict__ acls,
                        float* __restrict__ aself, float* __restrict__ aclsinT,
                        int EPL, int n_new, int B) {
    int i = blockIdx.x * 256 + threadIdx.x;
    if (i < EPL) {
        int s = csr[i];
        float ox = 0.f, oy = 0.f, oz = 0.f, ow = 0.f;
        if (s >= 0) {
            int d = csrd[i];
            float4 s4 = ((const float4*)als)[s];
            float4 d4 = ((const float4*)ald)[d];
            ox = elk(s4.x + d4.x);
            oy = elk(s4.y + d4.y);
            oz = elk(s4.z + d4.z);
            ow = elk(s4.w + d4.w);
        }
        a4T[i] = ox;
        a4T[(size_t)EPL + i] = oy;
        a4T[(size_t)2 * EPL + i] = oz;
        a4T[(size_t)3 * EPL + i] = ow;
        return;
    }
    int n = i - EPL;
    if (n < n_new) {
        float4 d4 = ((const float4*)ald)[n];
        float4 s4 = ((const float4*)als)[n];
        float4 o;
        o.x = elk(s4.x + d4.x);
        o.y = elk(s4.y + d4.y);
        o.z = elk(s4.z + d4.z);
        o.w = elk(s4.w + d4.w);
        ((float4*)aself)[n] = o;
        if (n >= B) {
            int c = batch[n - B];
            float4 cs = ((const float4*)als)[c];
            float4 p;
            p.x = elk(cs.x + d4.x);
            p.y = elk(cs.y + d4.y);
            p.z = elk(cs.z + d4.z);
            p.w = elk(cs.w + d4.w);
            ((float4*)acls)[n] = p;
            float4 cd = ((const float4*)ald)[c];
            aclsinT[n] = elk(s4.x + cd.x);
            aclsinT[(size_t)n_new + n] = elk(s4.y + cd.y);
            aclsinT[(size_t)2 * n_new + n] = elk(s4.z + cd.z);
            aclsinT[(size_t)3 * n_new + n] = elk(s4.w + cd.w);
        }
    }
}

// ---------------- MFMA GEMM: out[row][0:256] = A[row][0:K] @ W ----------------

template <int KS, bool ATT, bool BIAS>
__global__ __launch_bounds__(128, 1) void k_mgemm(
    const ushort* __restrict__ A, const ushort* __restrict__ Wf,
    const float* __restrict__ bias, ushort* __restrict__ outb,
    const float* __restrict__ att_s, const float* __restrict__ att_d,
    float* __restrict__ al_s, float* __restrict__ al_d, int rows)
{
    constexpr int K = KS * 32;
    int lane = threadIdx.x & 63, w = threadIdx.x >> 6;
    int rbase = blockIdx.x * 64 + w * 32;
    int arow0 = rbase + (lane & 15);
    int kofs = (lane >> 4) << 3;

    f32x4 acc[2][16];
#pragma unroll
    for (int mf = 0; mf < 2; ++mf)
#pragma unroll
        for (int nf = 0; nf < 16; ++nf) acc[mf][nf] = (f32x4){0.f, 0.f, 0.f, 0.f};

    const ushort* a0p = A + (size_t)arow0 * K + kofs;
    const ushort* a1p = a0p + (size_t)16 * K;
    bool g0 = arow0 < rows, g1 = (arow0 + 16) < rows;

#pragma unroll
    for (int kk = 0; kk < KS; ++kk) {
        bf16x8 af0 = {0, 0, 0, 0, 0, 0, 0, 0}, af1 = {0, 0, 0, 0, 0, 0, 0, 0};
        if (g0) af0 = *(const bf16x8*)(a0p + kk * 32);
        if (g1) af1 = *(const bf16x8*)(a1p + kk * 32);
        const bf16x8* wp = ((const bf16x8*)Wf) + (size_t)(kk * 16) * 64 + lane;
#pragma unroll
        for (int nf = 0; nf < 16; ++nf) {
            bf16x8 bv = wp[nf * 64];
            acc[0][nf] = __builtin_amdgcn_mfma_f32_16x16x32_bf16(af0, bv, acc[0][nf], 0, 0, 0);
            acc[1][nf] = __builtin_amdgcn_mfma_f32_16x16x32_bf16(af1, bv, acc[1][nf], 0, 0, 0);
        }
    }

    int rg = (lane >> 4) * 4;
    int c0 = lane & 15;
    float bv[16];
    if (BIAS) {
#pragma unroll
        for (int nf = 0; nf < 16; ++nf) bv[nf] = bias[nf * 16 + c0];
    }
#pragma unroll
    for (int mf = 0; mf < 2; ++mf)
#pragma unroll
        for (int r = 0; r < 4; ++r) {
            int row = rbase + mf * 16 + rg + r;
            if (row < rows) {
#pragma unroll
                for (int nf = 0; nf < 16; ++nf) {
                    float v = acc[mf][nf][r];
                    if (BIAS) v += bv[nf];
                    outb[(size_t)row * HID + nf * 16 + c0] = f2bf(v);
                }
            }
        }

    if (ATT) {
        float as[16], ad[16];
#pragma unroll
        for (int nf = 0; nf < 16; ++nf) {
            as[nf] = att_s[nf * 16 + c0];
            ad[nf] = att_d[nf * 16 + c0];
        }
#pragma unroll
        for (int mf = 0; mf < 2; ++mf)
#pragma unroll
            for (int r = 0; r < 4; ++r) {
                float ps[4] = {0.f, 0.f, 0.f, 0.f}, pd[4] = {0.f, 0.f, 0.f, 0.f};
#pragma unroll
                for (int nf = 0; nf < 16; ++nf) {
                    float v = acc[mf][nf][r];
                    ps[nf >> 2] += v * as[nf];
                    pd[nf >> 2] += v * ad[nf];
                }
#pragma unroll
                for (int o = 1; o < 16; o <<= 1) {
#pragma unroll
                    for (int h = 0; h < 4; ++h) {
                        ps[h] += __shfl_xor(ps[h], o, 64);
                        pd[h] += __shfl_xor(pd[h], o, 64);
                    }
                }
                int row = rbase + mf * 16 + rg + r;
                if (c0 == 0 && row < rows) {
                    float4 vs, vd;
                    vs.x = ps[0]; vs.y = ps[1]; vs.z = ps[2]; vs.w = ps[3];
                    vd.x = pd[0]; vd.y = pd[1]; vd.z = pd[2]; vd.w = pd[3];
                    *(float4*)(al_s + row * 4) = vs;
                    *(float4*)(al_d + row * 4) = vd;
                }
            }
    }
}

// ---------------- GAT aggregation + bias + residual + LayerNorm ----------------
// Branch-free batched gather: CSR segments padded to x8 (pad slots alpha=0,
// src clamped to row 0 which stays L1-hot). Per wave-iteration: 2 slots x
// {int4 srcs + float4 alphas + 4 independent 512B row gathers}; unroll 2 ->
// 16 rows (8KB) in flight per wave. One wave per node.
// lane = es(2 slots) x cg(32 groups of 8 ch); head = cg>>3.

__global__ __launch_bounds__(256, 4) void k_agg(
    const ushort* __restrict__ hb, const ushort* __restrict__ xs,
    const float* __restrict__ a4T, const float* __restrict__ acls,
    const float* __restrict__ aself, const float* __restrict__ aclsinT,
    const int* __restrict__ off, const int* __restrict__ csr,
    const int* __restrict__ batch, const int* __restrict__ lo,
    const int* __restrict__ hi,
    const float* __restrict__ b_gat, const float* __restrict__ ln_g,
    const float* __restrict__ ln_b,
    ushort* __restrict__ h_out, int n_new, int B, int EPL)
{
    int t = threadIdx.x, w = t >> 6, lane = t & 63;
    int n = blockIdx.x * 4 + w;
    if (n >= n_new) return;
    int es = lane >> 5, cg = lane & 31, head = cg >> 3;

    float acc[8] = {0.f, 0.f, 0.f, 0.f, 0.f, 0.f, 0.f, 0.f};
    float den = 0.f;

    if (n >= B) {
        int gbeg = off[n], gdegp = off[n + 1] - gbeg;   // multiple of 8
        int clssrc = batch[n - B];
        bf16x8 xcls  = *((const bf16x8*)(xs + (size_t)clssrc * HID) + cg);
        bf16x8 xself = *((const bf16x8*)(xs + (size_t)n * HID) + cg);
        float acl = acls[n * 4 + head];
        float asf = aself[n * 4 + head];

        const int4* cp = (const int4*)(csr + gbeg);
        const float4* ap = (const float4*)(a4T + (size_t)head * EPL + gbeg);
#pragma unroll 2
        for (int eb = 0; eb < gdegp; eb += 8) {
            int idx = (eb >> 2) + es;
            int4 s4 = cp[idx];
            float4 av = ap[idx];
            int s0 = s4.x < 0 ? 0 : s4.x;
            int s1 = s4.y < 0 ? 0 : s4.y;
            int s2 = s4.z < 0 ? 0 : s4.z;
            int s3 = s4.w < 0 ? 0 : s4.w;
            bf16x8 x0 = *((const bf16x8*)(xs + (size_t)s0 * HID) + cg);
            bf16x8 x1 = *((const bf16x8*)(xs + (size_t)s1 * HID) + cg);
            bf16x8 x2 = *((const bf16x8*)(xs + (size_t)s2 * HID) + cg);
            bf16x8 x3 = *((const bf16x8*)(xs + (size_t)s3 * HID) + cg);
            den += av.x + av.y + av.z + av.w;
#pragma unroll
            for (int j = 0; j < 8; ++j) {
                acc[j] += av.x * bf2f((unsigned short)x0[j]);
                acc[j] += av.y * bf2f((unsigned short)x1[j]);
                acc[j] += av.z * bf2f((unsigned short)x2[j]);
                acc[j] += av.w * bf2f((unsigned short)x3[j]);
            }
        }
        if (es == 0) {
            den += acl + asf;
#pragma unroll
            for (int j = 0; j < 8; ++j)
                acc[j] += acl * bf2f((unsigned short)xcls[j]) +
                          asf * bf2f((unsigned short)xself[j]);
        }
    } else {
        // CLS node: contiguous source range [B+lo, B+hi); weights planar.
        int cb = B + lo[n], cdeg = hi[n] - lo[n];
        bf16x8 xself = *((const bf16x8*)(xs + (size_t)n * HID) + cg);
        float asf = aself[n * 4 + head];
        const float* wp = aclsinT + (size_t)head * n_new;
        for (int eb = 0; eb < cdeg; eb += 8) {
            int b0 = eb + es * 4;
#pragma unroll
            for (int k = 0; k < 4; ++k) {
                int e = b0 + k;
                int ec = e < cdeg ? e : cdeg - 1;
                int src = cb + ec;
                float a = e < cdeg ? wp[src] : 0.f;
                bf16x8 xv = *((const bf16x8*)(xs + (size_t)src * HID) + cg);
                den += a;
#pragma unroll
                for (int j = 0; j < 8; ++j) acc[j] += a * bf2f((unsigned short)xv[j]);
            }
        }
        if (es == 0) {
            den += asf;
#pragma unroll
            for (int j = 0; j < 8; ++j) acc[j] += asf * bf2f((unsigned short)xself[j]);
        }
    }

    // reduce across the two edge slots (xor bit 5)
#pragma unroll
    for (int j = 0; j < 8; ++j) acc[j] += __shfl_xor(acc[j], 32, 64);
    den += __shfl_xor(den, 32, 64);
    float inv = 1.f / (den + 1e-16f);

    // residual + bias
    bf16x8 hv = *((const bf16x8*)(hb + (size_t)n * HID) + cg);
    const float4* bgp = (const float4*)(b_gat + cg * 8);
    float4 bg0 = bgp[0], bg1 = bgp[1];
    float bg[8] = {bg0.x, bg0.y, bg0.z, bg0.w, bg1.x, bg1.y, bg1.z, bg1.w};
    float r[8];
#pragma unroll
    for (int j = 0; j < 8; ++j)
        r[j] = bf2f((unsigned short)hv[j]) + acc[j] * inv + bg[j];

    // LayerNorm: butterfly over the 32 channel groups (bits 0..4)
    float ss = 0.f;
#pragma unroll
    for (int j = 0; j < 8; ++j) ss += r[j];
#pragma unroll
    for (int o = 1; o < 32; o <<= 1) ss += __shfl_xor(ss, o, 64);
    float mu = ss * (1.f / HID);
    float vv = 0.f;
#pragma unroll
    for (int j = 0; j < 8; ++j) { r[j] -= mu; vv += r[j] * r[j]; }
#pragma unroll
    for (int o = 1; o < 32; o <<= 1) vv += __shfl_xor(vv, o, 64);
    float rs = rsqrtf(vv * (1.f / HID) + EPS);

    if (es == 0) {
        const float4* gp = (const float4*)(ln_g + cg * 8);
        const float4* bp = (const float4*)(ln_b + cg * 8);
        float4 g0 = gp[0], g1 = gp[1];
        float4 lb0 = bp[0], lb1 = bp[1];
        float gg[8] = {g0.x, g0.y, g0.z, g0.w, g1.x, g1.y, g1.z, g1.w};
        float bb[8] = {lb0.x, lb0.y, lb0.z, lb0.w, lb1.x, lb1.y, lb1.z, lb1.w};
        bf16x8 o8;
#pragma unroll
        for (int j = 0; j < 8; ++j) o8[j] = (short)f2bf(r[j] * rs * gg[j] + bb[j]);
        *((bf16x8*)(h_out + (size_t)n * HID) + cg) = o8;
    }
}

// ---------------- output projection (B x 256 @ 256 x 256) ----------------

__global__ __launch_bounds__(256) void k_out(
    const ushort* __restrict__ h, const float* __restrict__ Wm,
    const float* __restrict__ bias, float* __restrict__ z)
{
    __shared__ float hs[HID];
    int b = blockIdx.x, t = threadIdx.x;
    hs[t] = bf2f(h[(size_t)b * HID + t]);
    __syncthreads();
    float acc = bias[t];
#pragma unroll 8
    for (int k = 0; k < HID; ++k) acc += hs[k] * Wm[k * HID + t];
    z[(size_t)b * HID + t] = acc;
}

// ---------------- launch ----------------

extern "C" void kernel_launch(void* const* d_in, const int* in_sizes, int n_in,
                              void* d_out, int out_size, void* d_ws, size_t ws_size,
                              hipStream_t stream) {
    const float* x      = (const float*)d_in[0];
    const int*   ei     = (const int*)d_in[1];
    const int*   batch  = (const int*)d_in[2];
    const float* W_in   = (const float*)d_in[3];
    const float* b_in   = (const float*)d_in[4];
    const float* cls    = (const float*)d_in[5];
    const float* W_gat  = (const float*)d_in[6];
    const float* att_s  = (const float*)d_in[7];
    const float* att_d  = (const float*)d_in[8];
    const float* b_gat  = (const float*)d_in[9];
    const float* ln_g   = (const float*)d_in[10];
    const float* ln_b   = (const float*)d_in[11];
    const float* W_out  = (const float*)d_in[12];
    const float* b_out  = (const float*)d_in[13];

    const int N = in_sizes[0] / 128;
    const int E = in_sizes[1] / 2;
    const int B = 64;
    const int n_new = N + B;
    const int EPL = E + 8 * n_new;        // padded CSR capacity
    const int* src0 = ei;
    const int* dst0 = ei + E;

    char* p = (char*)d_ws;
    auto alloc = [&](size_t bytes) -> void* {
        void* r = (void*)p;
        p += (bytes + 255) & ~(size_t)255;
        return r;
    };
    int*    off    = (int*)alloc((size_t)(n_new + 1) * 4);
    int*    deg    = (int*)alloc((size_t)n_new * 4);
    int*    cursor = (int*)alloc((size_t)n_new * 4);
    int*    csr    = (int*)alloc((size_t)EPL * 4);
    int*    csrd   = (int*)alloc((size_t)EPL * 4);
    int*    lo     = (int*)alloc((size_t)B * 4);
    int*    hi     = (int*)alloc((size_t)B * 4);
    ushort* xb     = (ushort*)alloc((size_t)N * 128 * 2);
    ushort* h0b    = (ushort*)alloc((size_t)n_new * HID * 2);
    ushort* h1b    = (ushort*)alloc((size_t)n_new * HID * 2);
    ushort* xsb    = (ushort*)alloc((size_t)n_new * HID * 2);
    float*  als    = (float*)alloc((size_t)n_new * 4 * 4);
    float*  aldv   = (float*)alloc((size_t)n_new * 4 * 4);
    float*  a4T    = (float*)alloc((size_t)EPL * 4 * 4);
    float*  acls   = (float*)alloc((size_t)n_new * 4 * 4);
    float*  aselfv = (float*)alloc((size_t)n_new * 4 * 4);
    float*  aclsinT= (float*)alloc((size_t)n_new * 4 * 4);
    ushort* wf_in  = (ushort*)alloc((size_t)4 * 1024 * 8 * 2);
    ushort* wf_gat = (ushort*)alloc((size_t)3 * 8 * 1024 * 8 * 2);

    const int nb_pre = (N * 128 / 4 + 255) / 256 + (n_new + 255) / 256 +
                       (EPL + 255) / 256 + (N + 255) / 256 +
                       (B * HID / 4 + 255) / 256 +
                       (4 * 1024 + 255) / 256 + (3 * 8 * 1024 + 255) / 256;
    k_pre<<<nb_pre, 256, 0, stream>>>(x, xb, cls, h0b, W_in, wf_in, W_gat, wf_gat,
                                      batch, lo, hi, deg, cursor, csr, N, B, n_new, EPL);
    k_count<<<(E + 255) / 256, 256, 0, stream>>>(dst0, deg, E, B);
    k_scan<<<1, 1024, 0, stream>>>(deg, off, n_new);
    k_fill<<<(E + 255) / 256, 256, 0, stream>>>(src0, dst0, off, cursor, csr, csrd, E, B);

    k_mgemm<4, false, true><<<(N + 63) / 64, 128, 0, stream>>>(
        xb, wf_in, b_in, h0b + (size_t)B * HID, nullptr, nullptr, nullptr, nullptr, N);

    const int nb_alpha = (EPL + n_new + 255) / 256;
    ushort* cur = h0b;
    ushort* nxt = h1b;
    for (int l = 0; l < 3; ++l) {
        k_mgemm<8, true, false><<<(n_new + 63) / 64, 128, 0, stream>>>(
            cur, wf_gat + (size_t)l * 65536, nullptr, xsb,
            att_s + l * HID, att_d + l * HID, als, aldv, n_new);
        k_alpha<<<nb_alpha, 256, 0, stream>>>(
            csr, csrd, als, aldv, batch, a4T, acls, aselfv, aclsinT, EPL, n_new, B);
        k_agg<<<(n_new + 3) / 4, 256, 0, stream>>>(
            cur, xsb, a4T, acls, aselfv, aclsinT, off, csr, batch, lo, hi,
            b_gat + l * HID, ln_g + l * HID, ln_b + l * HID, nxt, n_new, B, EPL);
        ushort* tmp = cur; cur = nxt; nxt = tmp;
    }
    k_out<<<B, 256, 0, stream>>>(cur, W_out, b_out, (float*)d_out);
}